// Round 1
// baseline (349.731 us; speedup 1.0000x reference)
//
#include <hip/hip_runtime.h>

// Problem constants
#define Bc 2
#define Sc 1024
#define Dc 1024
#define Hc 2048
#define Ec 8
#define Kc 2
#define Tc (Bc*Sc)      // 2048 tokens
#define Pc (Tc*Kc)      // 4096 jobs
#define PADROWS 128     // tile-overrun padding for Xg / hidden

typedef __bf16 bf16x8 __attribute__((ext_vector_type(8)));
typedef float floatx4 __attribute__((ext_vector_type(4)));
typedef unsigned short ushort4_t __attribute__((ext_vector_type(4)));

__device__ inline unsigned short f2bf(float f) {
    unsigned u = __builtin_bit_cast(unsigned, f);
    unsigned r = u + 0x7fffu + ((u >> 16) & 1u);   // RNE
    return (unsigned short)(r >> 16);
}

__device__ inline float gelu_tanh(float v) {
    // flax nn.gelu approximate=True
    return 0.5f * v * (1.0f + tanhf(0.7978845608028654f * (v + 0.044715f * v * v * v)));
}

// ---------- bucketing ----------
__global__ void count_kernel(const int* __restrict__ idx, int* __restrict__ counts) {
    int i = blockIdx.x * 256 + threadIdx.x;
    if (i < Pc) atomicAdd(&counts[idx[i]], 1);
}

__global__ void offsets_kernel(const int* __restrict__ counts, int* __restrict__ offs) {
    if (threadIdx.x == 0) {
        int s = 0;
        for (int e = 0; e < Ec; e++) { offs[e] = s; s += counts[e]; }
        offs[Ec] = s;
    }
}

__global__ void fill_kernel(const int* __restrict__ idx, const float* __restrict__ wts,
                            const int* __restrict__ offs, int* __restrict__ fill,
                            int* __restrict__ job_token, float* __restrict__ job_w) {
    int i = blockIdx.x * 256 + threadIdx.x;
    if (i < Pc) {
        int e = idx[i];
        int pos = offs[e] + atomicAdd(&fill[e], 1);
        job_token[pos] = i >> 1;          // token id (i = t*K + k)
        job_w[pos] = wts[i];
    }
}

// ---------- fp32 -> bf16 weight conversion ----------
__global__ void convert_kernel(const float* __restrict__ src, unsigned short* __restrict__ dst, int n4) {
    int i = blockIdx.x * blockDim.x + threadIdx.x;
    if (i < n4) {
        float4 v = ((const float4*)src)[i];
        ushort4_t o = { f2bf(v.x), f2bf(v.y), f2bf(v.z), f2bf(v.w) };
        ((ushort4_t*)dst)[i] = o;
    }
}

// ---------- gather selected x rows into compact bf16 matrix ----------
__global__ void gather_kernel(const float* __restrict__ x, const int* __restrict__ job_token,
                              unsigned short* __restrict__ Xg) {
    int row = blockIdx.x;                  // 0..Pc-1
    int tok = job_token[row];
    int j = threadIdx.x;                   // 256 threads x 4 elems = 1024
    float4 v = ((const float4*)(x + (size_t)tok * Dc))[j];
    ushort4_t o = { f2bf(v.x), f2bf(v.y), f2bf(v.z), f2bf(v.w) };
    *(ushort4_t*)(Xg + (size_t)row * Dc + j * 4) = o;
}

// ---------- GEMM tile config ----------
#define BM 128
#define BN 128
#define BK 32

// GEMM1: hidden[m, n] = gelu( sum_d Xg[m,d] * keys[e][n,d] ),  K=1024, N=2048
__global__ __launch_bounds__(256, 2) void gemm1_kernel(
    const unsigned short* __restrict__ Xg,      // [Pc+PADROWS, 1024] bf16
    const unsigned short* __restrict__ keysb,   // [E, 2048, 1024] bf16
    const int* __restrict__ counts, const int* __restrict__ offs,
    unsigned short* __restrict__ hidden)        // [Pc+PADROWS, 2048] bf16
{
    int e = blockIdx.z;
    int cnt = counts[e];
    int m0 = blockIdx.y * BM;
    if (m0 >= cnt) return;
    int moff = offs[e];
    int n0 = blockIdx.x * BN;
    const unsigned short* Ag = Xg + (size_t)(moff + m0) * Dc;
    const unsigned short* Bg = keysb + (size_t)e * Hc * Dc + (size_t)n0 * Dc;

    __shared__ unsigned short As[BM * BK];
    __shared__ unsigned short Bs[BN * BK];

    int t = threadIdx.x;
    int lane = t & 63, w = t >> 6;
    int Mq = (w & 1) * 64, Nq = (w >> 1) * 64;
    int l15 = lane & 15, l4 = lane >> 4;

    floatx4 acc[4][4];
#pragma unroll
    for (int i = 0; i < 4; i++)
#pragma unroll
        for (int j = 0; j < 4; j++) acc[i][j] = (floatx4){0.f, 0.f, 0.f, 0.f};

    int c0 = t, c1 = t + 256;
    int r0 = c0 >> 2, kc0 = c0 & 3;
    int r1 = c1 >> 2, kc1 = c1 & 3;

    for (int kk = 0; kk < Dc; kk += BK) {
        __syncthreads();
        uint4 a0 = *(const uint4*)(Ag + (size_t)r0 * Dc + kk + kc0 * 8);
        uint4 a1 = *(const uint4*)(Ag + (size_t)r1 * Dc + kk + kc1 * 8);
        uint4 b0 = *(const uint4*)(Bg + (size_t)r0 * Dc + kk + kc0 * 8);
        uint4 b1 = *(const uint4*)(Bg + (size_t)r1 * Dc + kk + kc1 * 8);
        *(uint4*)(As + c0 * 8) = a0;
        *(uint4*)(As + c1 * 8) = a1;
        *(uint4*)(Bs + c0 * 8) = b0;
        *(uint4*)(Bs + c1 * 8) = b1;
        __syncthreads();
        bf16x8 af[4], bfr[4];
#pragma unroll
        for (int mi = 0; mi < 4; mi++)
            af[mi] = *(const bf16x8*)(As + (Mq + mi * 16 + l15) * BK + l4 * 8);
#pragma unroll
        for (int ni = 0; ni < 4; ni++)
            bfr[ni] = *(const bf16x8*)(Bs + (Nq + ni * 16 + l15) * BK + l4 * 8);
#pragma unroll
        for (int mi = 0; mi < 4; mi++)
#pragma unroll
            for (int ni = 0; ni < 4; ni++)
                acc[mi][ni] = __builtin_amdgcn_mfma_f32_16x16x32_bf16(af[mi], bfr[ni], acc[mi][ni], 0, 0, 0);
    }

#pragma unroll
    for (int mi = 0; mi < 4; mi++) {
#pragma unroll
        for (int r = 0; r < 4; r++) {
            int mloc = Mq + mi * 16 + l4 * 4 + r;
            int gm = m0 + mloc;
            if (gm < cnt) {
                size_t rowbase = (size_t)(moff + gm) * Hc + n0;
#pragma unroll
                for (int ni = 0; ni < 4; ni++) {
                    float g = gelu_tanh(acc[mi][ni][r]);
                    hidden[rowbase + Nq + ni * 16 + l15] = f2bf(g);
                }
            }
        }
    }
}

// GEMM2: out[token, n] += w * sum_h hidden[m,h] * values[e][n,h],  K=2048, N=1024
__global__ __launch_bounds__(256, 2) void gemm2_kernel(
    const unsigned short* __restrict__ hidden,  // [Pc+PADROWS, 2048] bf16
    const unsigned short* __restrict__ valsb,   // [E, 1024, 2048] bf16
    const int* __restrict__ counts, const int* __restrict__ offs,
    const int* __restrict__ job_token, const float* __restrict__ job_w,
    float* __restrict__ out)
{
    int e = blockIdx.z;
    int cnt = counts[e];
    int m0 = blockIdx.y * BM;
    if (m0 >= cnt) return;
    int moff = offs[e];
    int n0 = blockIdx.x * BN;
    const unsigned short* Ag = hidden + (size_t)(moff + m0) * Hc;
    const unsigned short* Bg = valsb + (size_t)e * Dc * Hc + (size_t)n0 * Hc;

    __shared__ unsigned short As[BM * BK];
    __shared__ unsigned short Bs[BN * BK];

    int t = threadIdx.x;
    int lane = t & 63, w = t >> 6;
    int Mq = (w & 1) * 64, Nq = (w >> 1) * 64;
    int l15 = lane & 15, l4 = lane >> 4;

    floatx4 acc[4][4];
#pragma unroll
    for (int i = 0; i < 4; i++)
#pragma unroll
        for (int j = 0; j < 4; j++) acc[i][j] = (floatx4){0.f, 0.f, 0.f, 0.f};

    int c0 = t, c1 = t + 256;
    int r0 = c0 >> 2, kc0 = c0 & 3;
    int r1 = c1 >> 2, kc1 = c1 & 3;

    for (int kk = 0; kk < Hc; kk += BK) {
        __syncthreads();
        uint4 a0 = *(const uint4*)(Ag + (size_t)r0 * Hc + kk + kc0 * 8);
        uint4 a1 = *(const uint4*)(Ag + (size_t)r1 * Hc + kk + kc1 * 8);
        uint4 b0 = *(const uint4*)(Bg + (size_t)r0 * Hc + kk + kc0 * 8);
        uint4 b1 = *(const uint4*)(Bg + (size_t)r1 * Hc + kk + kc1 * 8);
        *(uint4*)(As + c0 * 8) = a0;
        *(uint4*)(As + c1 * 8) = a1;
        *(uint4*)(Bs + c0 * 8) = b0;
        *(uint4*)(Bs + c1 * 8) = b1;
        __syncthreads();
        bf16x8 af[4], bfr[4];
#pragma unroll
        for (int mi = 0; mi < 4; mi++)
            af[mi] = *(const bf16x8*)(As + (Mq + mi * 16 + l15) * BK + l4 * 8);
#pragma unroll
        for (int ni = 0; ni < 4; ni++)
            bfr[ni] = *(const bf16x8*)(Bs + (Nq + ni * 16 + l15) * BK + l4 * 8);
#pragma unroll
        for (int mi = 0; mi < 4; mi++)
#pragma unroll
            for (int ni = 0; ni < 4; ni++)
                acc[mi][ni] = __builtin_amdgcn_mfma_f32_16x16x32_bf16(af[mi], bfr[ni], acc[mi][ni], 0, 0, 0);
    }

#pragma unroll
    for (int mi = 0; mi < 4; mi++) {
#pragma unroll
        for (int r = 0; r < 4; r++) {
            int mloc = Mq + mi * 16 + l4 * 4 + r;
            int gm = m0 + mloc;
            if (gm < cnt) {
                int tok = job_token[moff + gm];
                float wgt = job_w[moff + gm];
                float* orow = out + (size_t)tok * Dc + n0;
#pragma unroll
                for (int ni = 0; ni < 4; ni++) {
                    atomicAdd(orow + Nq + ni * 16 + l15, wgt * acc[mi][ni][r]);
                }
            }
        }
    }
}

// ---------- workspace layout (bytes) ----------
// counts     @ 0        (32)
// fill       @ 32       (32)
// offs       @ 64       (36) -> pad
// job_token  @ 128      (16384)
// job_w      @ 16512    (16384)
// Xg         @ 33024    ((4096+128)*1024*2 = 8650752)
// keysb      @ 8683776  (33554432)
// valsb      @ 42238208 (33554432)
// hidden     @ 75792640 ((4096+128)*2048*2 = 17301504)  -> total 93094144 B

extern "C" void kernel_launch(void* const* d_in, const int* in_sizes, int n_in,
                              void* d_out, int out_size, void* d_ws, size_t ws_size,
                              hipStream_t stream) {
    const float* x      = (const float*)d_in[0];
    const float* keys   = (const float*)d_in[1];
    const float* values = (const float*)d_in[2];
    const int*   eidx   = (const int*)d_in[3];
    const float* ew     = (const float*)d_in[4];
    float* out = (float*)d_out;
    char* ws = (char*)d_ws;

    int*   counts    = (int*)(ws + 0);
    int*   fill      = (int*)(ws + 32);
    int*   offs      = (int*)(ws + 64);
    int*   job_token = (int*)(ws + 128);
    float* job_w     = (float*)(ws + 16512);
    unsigned short* Xg     = (unsigned short*)(ws + 33024);
    unsigned short* keysb  = (unsigned short*)(ws + 8683776);
    unsigned short* valsb  = (unsigned short*)(ws + 42238208);
    unsigned short* hidden = (unsigned short*)(ws + 75792640);

    hipMemsetAsync(ws, 0, 128, stream);                       // counts/fill/offs
    hipMemsetAsync(d_out, 0, (size_t)out_size * 4, stream);   // fp32 accum target

    count_kernel<<<16, 256, 0, stream>>>(eidx, counts);
    offsets_kernel<<<1, 64, 0, stream>>>(counts, offs);
    fill_kernel<<<16, 256, 0, stream>>>(eidx, ew, offs, fill, job_token, job_w);

    convert_kernel<<<16384, 256, 0, stream>>>(keys, keysb, (Ec * Hc * Dc) / 4);
    convert_kernel<<<16384, 256, 0, stream>>>(values, valsb, (Ec * Dc * Hc) / 4);
    gather_kernel<<<Pc, 256, 0, stream>>>(x, job_token, Xg);

    gemm1_kernel<<<dim3(Hc / BN, 32, Ec), 256, 0, stream>>>(Xg, keysb, counts, offs, hidden);
    gemm2_kernel<<<dim3(Dc / BN, 32, Ec), 256, 0, stream>>>(hidden, valsb, counts, offs, job_token, job_w, out);
}

// Round 2
// 309.025 us; speedup vs baseline: 1.1317x; 1.1317x over previous
//
#include <hip/hip_runtime.h>

// Problem constants
#define Bc 2
#define Sc 1024
#define Dc 1024
#define Hc 2048
#define Ec 8
#define Kc 2
#define Tc (Bc*Sc)      // 2048 tokens
#define Pc (Tc*Kc)      // 4096 jobs
#define PADROWS 128     // tile-overrun padding for Xg / hidden
#define MAXTILES 40     // sum_e ceil(cnt_e/128) <= 4096/128 + 8 = 40

typedef __bf16 bf16x8 __attribute__((ext_vector_type(8)));
typedef float floatx4 __attribute__((ext_vector_type(4)));
typedef unsigned short ushort4_t __attribute__((ext_vector_type(4)));
typedef unsigned short ushort8_t __attribute__((ext_vector_type(8)));

__device__ inline unsigned short f2bf(float f) {
    unsigned u = __builtin_bit_cast(unsigned, f);
    unsigned r = u + 0x7fffu + ((u >> 16) & 1u);   // RNE
    return (unsigned short)(r >> 16);
}

__device__ inline float gelu_tanh(float v) {
    // flax nn.gelu approximate=True
    return 0.5f * v * (1.0f + tanhf(0.7978845608028654f * (v + 0.044715f * v * v * v)));
}

// async global->LDS, 16B per lane; LDS dest = wave-uniform base + lane*16
__device__ inline void gload_lds16(const void* g, void* l) {
    __builtin_amdgcn_global_load_lds((const __attribute__((address_space(1))) unsigned int*)g,
                                     (__attribute__((address_space(3))) unsigned int*)l,
                                     16, 0, 0);
}

// ---------- bucketing ----------
__global__ void count_kernel(const int* __restrict__ idx, int* __restrict__ counts) {
    int i = blockIdx.x * 256 + threadIdx.x;
    if (i < Pc) atomicAdd(&counts[idx[i]], 1);
}

__global__ void offsets_kernel(const int* __restrict__ counts, int* __restrict__ offs,
                               int* __restrict__ tile_e, int* __restrict__ tile_m0,
                               int* __restrict__ n_tiles) {
    if (threadIdx.x == 0) {
        int s = 0, t = 0;
        for (int e = 0; e < Ec; e++) {
            offs[e] = s;
            for (int m0 = 0; m0 < counts[e]; m0 += 128) { tile_e[t] = e; tile_m0[t] = m0; t++; }
            s += counts[e];
        }
        offs[Ec] = s;
        *n_tiles = t;
    }
}

__global__ void fill_kernel(const int* __restrict__ idx, const float* __restrict__ wts,
                            const int* __restrict__ offs, int* __restrict__ fill,
                            int* __restrict__ job_token, float* __restrict__ job_w) {
    int i = blockIdx.x * 256 + threadIdx.x;
    if (i < Pc) {
        int e = idx[i];
        int pos = offs[e] + atomicAdd(&fill[e], 1);
        job_token[pos] = i >> 1;          // token id (i = t*K + k)
        job_w[pos] = wts[i];
    }
}

// ---------- fp32 -> bf16 weight conversion (32B read / 16B write per thread) ----------
__global__ void convert_kernel(const float* __restrict__ src, unsigned short* __restrict__ dst, int n8) {
    int i = blockIdx.x * 256 + threadIdx.x;
    if (i < n8) {
        float4 v0 = ((const float4*)src)[2 * i];
        float4 v1 = ((const float4*)src)[2 * i + 1];
        ushort8_t o = { f2bf(v0.x), f2bf(v0.y), f2bf(v0.z), f2bf(v0.w),
                        f2bf(v1.x), f2bf(v1.y), f2bf(v1.z), f2bf(v1.w) };
        ((ushort8_t*)dst)[i] = o;
    }
}

// ---------- gather selected x rows into compact bf16 matrix ----------
__global__ void gather_kernel(const float* __restrict__ x, const int* __restrict__ job_token,
                              unsigned short* __restrict__ Xg) {
    int row = blockIdx.x;                  // 0..Pc-1
    int tok = job_token[row];
    int j = threadIdx.x;                   // 256 threads x 4 elems = 1024
    float4 v = ((const float4*)(x + (size_t)tok * Dc))[j];
    ushort4_t o = { f2bf(v.x), f2bf(v.y), f2bf(v.z), f2bf(v.w) };
    *(ushort4_t*)(Xg + (size_t)row * Dc + j * 4) = o;
}

// ---------- GEMM tile config ----------
#define BM 128
#define BN 128
#define BK 32

// stage a 128x32 bf16 tile (row-major, ld=ldst) into LDS via global_load_lds
// wave w covers rows [w*32, w*32+32) in two 16-row chunks; lane i -> base+i*16B
__device__ inline void stage_tile(const unsigned short* __restrict__ gbase, size_t ldst, int kk,
                                  unsigned short* lds, int w, int lane) {
#pragma unroll
    for (int s = 0; s < 2; s++) {
        int row = w * 32 + s * 16 + (lane >> 2);
        const char* g = (const char*)gbase + ((size_t)row * ldst + kk) * 2 + (size_t)(lane & 3) * 16;
        char* l = (char*)lds + (size_t)(w * 32 + s * 16) * 64;
        gload_lds16(g, l);
    }
}

// GEMM1: hidden[m, n] = gelu( sum_d Xg[m,d] * keys[e][n,d] ),  K=1024, N=2048
__global__ __launch_bounds__(256, 2) void gemm1_kernel(
    const unsigned short* __restrict__ Xg,      // [Pc+PADROWS, 1024] bf16
    const unsigned short* __restrict__ keysb,   // [E, 2048, 1024] bf16
    const int* __restrict__ counts, const int* __restrict__ offs,
    const int* __restrict__ tile_e, const int* __restrict__ tile_m0,
    const int* __restrict__ n_tiles,
    unsigned short* __restrict__ hidden)        // [Pc+PADROWS, 2048] bf16
{
    int ty = blockIdx.y;
    if (ty >= *n_tiles) return;
    int e = tile_e[ty], m0 = tile_m0[ty];
    int cnt = counts[e], moff = offs[e];
    int n0 = blockIdx.x * BN;
    const unsigned short* Ag = Xg + (size_t)(moff + m0) * Dc;
    const unsigned short* Bg = keysb + (size_t)e * Hc * Dc + (size_t)n0 * Dc;

    __shared__ unsigned short As[BM * BK];
    __shared__ unsigned short Bs[BN * BK];

    int t = threadIdx.x;
    int lane = t & 63, w = t >> 6;
    int Mq = (w & 1) * 64, Nq = (w >> 1) * 64;
    int l15 = lane & 15, l4 = lane >> 4;

    floatx4 acc[4][4];
#pragma unroll
    for (int i = 0; i < 4; i++)
#pragma unroll
        for (int j = 0; j < 4; j++) acc[i][j] = (floatx4){0.f, 0.f, 0.f, 0.f};

    for (int kk = 0; kk < Dc; kk += BK) {
        __syncthreads();
        stage_tile(Ag, Dc, kk, As, w, lane);
        stage_tile(Bg, Dc, kk, Bs, w, lane);
        __syncthreads();
        bf16x8 af[4], bfr[4];
#pragma unroll
        for (int mi = 0; mi < 4; mi++)
            af[mi] = *(const bf16x8*)(As + (Mq + mi * 16 + l15) * BK + l4 * 8);
#pragma unroll
        for (int ni = 0; ni < 4; ni++)
            bfr[ni] = *(const bf16x8*)(Bs + (Nq + ni * 16 + l15) * BK + l4 * 8);
#pragma unroll
        for (int mi = 0; mi < 4; mi++)
#pragma unroll
            for (int ni = 0; ni < 4; ni++)
                acc[mi][ni] = __builtin_amdgcn_mfma_f32_16x16x32_bf16(af[mi], bfr[ni], acc[mi][ni], 0, 0, 0);
    }

#pragma unroll
    for (int mi = 0; mi < 4; mi++) {
#pragma unroll
        for (int r = 0; r < 4; r++) {
            int mloc = Mq + mi * 16 + l4 * 4 + r;
            int gm = m0 + mloc;
            if (gm < cnt) {
                size_t rowbase = (size_t)(moff + gm) * Hc + n0;
#pragma unroll
                for (int ni = 0; ni < 4; ni++) {
                    float g = gelu_tanh(acc[mi][ni][r]);
                    hidden[rowbase + Nq + ni * 16 + l15] = f2bf(g);
                }
            }
        }
    }
}

// GEMM2: out[token, n] += w * sum_h hidden[m,h] * values[e][n,h]
// split-K: blockIdx.z selects K-half (2 x 1024)
__global__ __launch_bounds__(256, 2) void gemm2_kernel(
    const unsigned short* __restrict__ hidden,  // [Pc+PADROWS, 2048] bf16
    const unsigned short* __restrict__ valsb,   // [E, 1024, 2048] bf16
    const int* __restrict__ counts, const int* __restrict__ offs,
    const int* __restrict__ tile_e, const int* __restrict__ tile_m0,
    const int* __restrict__ n_tiles,
    const int* __restrict__ job_token, const float* __restrict__ job_w,
    float* __restrict__ out)
{
    int ty = blockIdx.y;
    if (ty >= *n_tiles) return;
    int e = tile_e[ty], m0 = tile_m0[ty];
    int cnt = counts[e], moff = offs[e];
    int n0 = blockIdx.x * BN;
    int k_begin = blockIdx.z * (Hc / 2);
    int k_end = k_begin + (Hc / 2);
    const unsigned short* Ag = hidden + (size_t)(moff + m0) * Hc;
    const unsigned short* Bg = valsb + (size_t)e * Dc * Hc + (size_t)n0 * Hc;

    __shared__ unsigned short As[BM * BK];
    __shared__ unsigned short Bs[BN * BK];

    int t = threadIdx.x;
    int lane = t & 63, w = t >> 6;
    int Mq = (w & 1) * 64, Nq = (w >> 1) * 64;
    int l15 = lane & 15, l4 = lane >> 4;

    floatx4 acc[4][4];
#pragma unroll
    for (int i = 0; i < 4; i++)
#pragma unroll
        for (int j = 0; j < 4; j++) acc[i][j] = (floatx4){0.f, 0.f, 0.f, 0.f};

    for (int kk = k_begin; kk < k_end; kk += BK) {
        __syncthreads();
        stage_tile(Ag, Hc, kk, As, w, lane);
        stage_tile(Bg, Hc, kk, Bs, w, lane);
        __syncthreads();
        bf16x8 af[4], bfr[4];
#pragma unroll
        for (int mi = 0; mi < 4; mi++)
            af[mi] = *(const bf16x8*)(As + (Mq + mi * 16 + l15) * BK + l4 * 8);
#pragma unroll
        for (int ni = 0; ni < 4; ni++)
            bfr[ni] = *(const bf16x8*)(Bs + (Nq + ni * 16 + l15) * BK + l4 * 8);
#pragma unroll
        for (int mi = 0; mi < 4; mi++)
#pragma unroll
            for (int ni = 0; ni < 4; ni++)
                acc[mi][ni] = __builtin_amdgcn_mfma_f32_16x16x32_bf16(af[mi], bfr[ni], acc[mi][ni], 0, 0, 0);
    }

#pragma unroll
    for (int mi = 0; mi < 4; mi++) {
#pragma unroll
        for (int r = 0; r < 4; r++) {
            int mloc = Mq + mi * 16 + l4 * 4 + r;
            int gm = m0 + mloc;
            if (gm < cnt) {
                int tok = job_token[moff + gm];
                float wgt = job_w[moff + gm];
                float* orow = out + (size_t)tok * Dc + n0;
#pragma unroll
                for (int ni = 0; ni < 4; ni++) {
                    atomicAdd(orow + Nq + ni * 16 + l15, wgt * acc[mi][ni][r]);
                }
            }
        }
    }
}

// ---------- workspace layout (bytes) ----------
// counts     @ 0        (32)
// fill       @ 32       (32)
// offs       @ 64       (36 -> pad to 128)
// tile_e     @ 128      (160 -> pad 192)
// tile_m0    @ 320      (160 -> pad 192)
// n_tiles    @ 512      (4 -> pad 128)
// job_token  @ 640      (16384)
// job_w      @ 17024    (16384)
// Xg         @ 33408    ((4096+128)*1024*2 = 8650752)
// keysb      @ 8684160  (33554432)
// valsb      @ 42238592 (33554432)
// hidden     @ 75793024 ((4096+128)*2048*2 = 17301504) -> total 93094528 B

extern "C" void kernel_launch(void* const* d_in, const int* in_sizes, int n_in,
                              void* d_out, int out_size, void* d_ws, size_t ws_size,
                              hipStream_t stream) {
    const float* x      = (const float*)d_in[0];
    const float* keys   = (const float*)d_in[1];
    const float* values = (const float*)d_in[2];
    const int*   eidx   = (const int*)d_in[3];
    const float* ew     = (const float*)d_in[4];
    float* out = (float*)d_out;
    char* ws = (char*)d_ws;

    int*   counts    = (int*)(ws + 0);
    int*   fill      = (int*)(ws + 32);
    int*   offs      = (int*)(ws + 64);
    int*   tile_e    = (int*)(ws + 128);
    int*   tile_m0   = (int*)(ws + 320);
    int*   n_tiles   = (int*)(ws + 512);
    int*   job_token = (int*)(ws + 640);
    float* job_w     = (float*)(ws + 17024);
    unsigned short* Xg     = (unsigned short*)(ws + 33408);
    unsigned short* keysb  = (unsigned short*)(ws + 8684160);
    unsigned short* valsb  = (unsigned short*)(ws + 42238592);
    unsigned short* hidden = (unsigned short*)(ws + 75793024);

    hipMemsetAsync(ws, 0, 640, stream);                       // counts/fill/offs/tiles
    hipMemsetAsync(d_out, 0, (size_t)out_size * 4, stream);   // fp32 accum target

    count_kernel<<<16, 256, 0, stream>>>(eidx, counts);
    offsets_kernel<<<1, 64, 0, stream>>>(counts, offs, tile_e, tile_m0, n_tiles);
    fill_kernel<<<16, 256, 0, stream>>>(eidx, ew, offs, fill, job_token, job_w);

    convert_kernel<<<8192, 256, 0, stream>>>(keys, keysb, (Ec * Hc * Dc) / 8);
    convert_kernel<<<8192, 256, 0, stream>>>(values, valsb, (Ec * Dc * Hc) / 8);
    gather_kernel<<<Pc, 256, 0, stream>>>(x, job_token, Xg);

    gemm1_kernel<<<dim3(Hc / BN, MAXTILES, 1), 256, 0, stream>>>(
        Xg, keysb, counts, offs, tile_e, tile_m0, n_tiles, hidden);
    gemm2_kernel<<<dim3(Dc / BN, MAXTILES, 2), 256, 0, stream>>>(
        hidden, valsb, counts, offs, tile_e, tile_m0, n_tiles, job_token, job_w, out);
}

// Round 3
// 283.661 us; speedup vs baseline: 1.2329x; 1.0894x over previous
//
#include <hip/hip_runtime.h>

// Problem constants
#define Bc 2
#define Sc 1024
#define Dc 1024
#define Hc 2048
#define Ec 8
#define Kc 2
#define Tc (Bc*Sc)      // 2048 tokens
#define Pc (Tc*Kc)      // 4096 jobs
#define PADROWS 128     // tile-overrun padding for Xg / hidden
#define MAXTILES 40     // sum_e ceil(cnt_e/128) <= 4096/128 + 8 = 40

typedef __bf16 bf16x8 __attribute__((ext_vector_type(8)));
typedef float floatx4 __attribute__((ext_vector_type(4)));
typedef unsigned short ushort4_t __attribute__((ext_vector_type(4)));
typedef unsigned short ushort8_t __attribute__((ext_vector_type(8)));

__device__ inline unsigned short f2bf(float f) {
    unsigned u = __builtin_bit_cast(unsigned, f);
    unsigned r = u + 0x7fffu + ((u >> 16) & 1u);   // RNE
    return (unsigned short)(r >> 16);
}

__device__ inline float gelu_tanh(float v) {
    // flax nn.gelu approximate=True
    return 0.5f * v * (1.0f + tanhf(0.7978845608028654f * (v + 0.044715f * v * v * v)));
}

// async global->LDS, 16B per lane; LDS dest = wave-uniform base + lane*16
__device__ inline void gload_lds16(const void* g, void* l) {
    __builtin_amdgcn_global_load_lds((const __attribute__((address_space(1))) unsigned int*)g,
                                     (__attribute__((address_space(3))) unsigned int*)l,
                                     16, 0, 0);
}

// ---------- single-block bucketing: counts + prefix + tile list + job fill ----------
__global__ void bucket_kernel(const int* __restrict__ idx, const float* __restrict__ wts,
                              int* __restrict__ counts, int* __restrict__ offs,
                              int* __restrict__ tile_e, int* __restrict__ tile_m0,
                              int* __restrict__ n_tiles,
                              int* __restrict__ job_token, float* __restrict__ job_w) {
    __shared__ int lc[Ec], lf[Ec], lo[Ec];
    int t = threadIdx.x;
    if (t < Ec) { lc[t] = 0; lf[t] = 0; }
    __syncthreads();
    int myid[Pc / 256];
#pragma unroll
    for (int j = 0; j < Pc / 256; j++) {
        int i = t + j * 256;
        myid[j] = idx[i];
        atomicAdd(&lc[myid[j]], 1);
    }
    __syncthreads();
    if (t == 0) {
        int s = 0, tt = 0;
        for (int e = 0; e < Ec; e++) {
            lo[e] = s; offs[e] = s; counts[e] = lc[e];
            for (int m0 = 0; m0 < lc[e]; m0 += 128) { tile_e[tt] = e; tile_m0[tt] = m0; tt++; }
            s += lc[e];
        }
        offs[Ec] = s;
        *n_tiles = tt;
    }
    __syncthreads();
#pragma unroll
    for (int j = 0; j < Pc / 256; j++) {
        int i = t + j * 256;
        int e = myid[j];
        int pos = lo[e] + atomicAdd(&lf[e], 1);
        job_token[pos] = i >> 1;          // i = token*K + k
        job_w[pos] = wts[i];
    }
}

// ---------- fp32 -> bf16 conversion of BOTH weight tensors in one launch ----------
__global__ void convert2_kernel(const float* __restrict__ a, unsigned short* __restrict__ da,
                                const float* __restrict__ b, unsigned short* __restrict__ db,
                                int n8each) {
    int i = blockIdx.x * 256 + threadIdx.x;
    const float* s; unsigned short* d; int j;
    if (i < n8each) { s = a; d = da; j = i; }
    else            { s = b; d = db; j = i - n8each; if (j >= n8each) return; }
    float4 v0 = ((const float4*)s)[2 * j];
    float4 v1 = ((const float4*)s)[2 * j + 1];
    ushort8_t o = { f2bf(v0.x), f2bf(v0.y), f2bf(v0.z), f2bf(v0.w),
                    f2bf(v1.x), f2bf(v1.y), f2bf(v1.z), f2bf(v1.w) };
    ((ushort8_t*)d)[j] = o;
}

// ---------- gather selected x rows into compact bf16 matrix ----------
__global__ void gather_kernel(const float* __restrict__ x, const int* __restrict__ job_token,
                              unsigned short* __restrict__ Xg) {
    int row = blockIdx.x;                  // 0..Pc-1
    int tok = job_token[row];
    int j = threadIdx.x;                   // 256 threads x 4 elems = 1024
    float4 v = ((const float4*)(x + (size_t)tok * Dc))[j];
    ushort4_t o = { f2bf(v.x), f2bf(v.y), f2bf(v.z), f2bf(v.w) };
    *(ushort4_t*)(Xg + (size_t)row * Dc + j * 4) = o;
}

// ---------- GEMM tile config ----------
#define BM 128
#define BN 64
#define BK 32
// block = 256 threads = 4 waves; wave quadrant: Mq=(w&1)*64, Nq=(w>>1)*32
// wave tile 64x32 -> 4x2 of 16x16x32 MFMA, acc = 8 x floatx4

// stage A tile 128x32: wave w covers rows [w*32, w*32+32) in two 16-row chunks
// stage B tile 64x32:  wave w covers rows [w*16, w*16+16) in one chunk
// each 16-row chunk: lane i -> row chunk+ (i>>2), 16B at col (i&3)*16; LDS = base + lane*16
__device__ inline void stage_ab(const unsigned short* __restrict__ Ag, size_t lda,
                                const unsigned short* __restrict__ Bg, size_t ldb,
                                int kk, unsigned short* As, unsigned short* Bs,
                                int w, int lane) {
    int lr = lane >> 2;
    size_t lcb = (size_t)(lane & 3) * 16;
#pragma unroll
    for (int s = 0; s < 2; s++) {
        int row = w * 32 + s * 16 + lr;
        const char* g = (const char*)(Ag + (size_t)row * lda + kk) + lcb;
        gload_lds16(g, (char*)As + (size_t)(w * 32 + s * 16) * 64);
    }
    {
        int row = w * 16 + lr;
        const char* g = (const char*)(Bg + (size_t)row * ldb + kk) + lcb;
        gload_lds16(g, (char*)Bs + (size_t)(w * 16) * 64);
    }
}

// GEMM1: hidden[m, n] = gelu( sum_d Xg[m,d] * keys[e][n,d] ),  K=1024, N=2048
__global__ __launch_bounds__(256, 4) void gemm1_kernel(
    const unsigned short* __restrict__ Xg,      // [Pc+PADROWS, 1024] bf16
    const unsigned short* __restrict__ keysb,   // [E, 2048, 1024] bf16
    const int* __restrict__ counts, const int* __restrict__ offs,
    const int* __restrict__ tile_e, const int* __restrict__ tile_m0,
    const int* __restrict__ n_tiles,
    unsigned short* __restrict__ hidden)        // [Pc+PADROWS, 2048] bf16
{
    int ty = blockIdx.y;
    if (ty >= *n_tiles) return;
    int e = tile_e[ty], m0 = tile_m0[ty];
    int cnt = counts[e], moff = offs[e];
    int n0 = blockIdx.x * BN;
    const unsigned short* Ag = Xg + (size_t)(moff + m0) * Dc;
    const unsigned short* Bg = keysb + (size_t)e * Hc * Dc + (size_t)n0 * Dc;

    __shared__ unsigned short As[BM * BK];
    __shared__ unsigned short Bs[BN * BK];

    int t = threadIdx.x;
    int lane = t & 63, w = t >> 6;
    int Mq = (w & 1) * 64, Nq = (w >> 1) * 32;
    int l15 = lane & 15, l4 = lane >> 4;

    floatx4 acc[4][2];
#pragma unroll
    for (int i = 0; i < 4; i++)
#pragma unroll
        for (int j = 0; j < 2; j++) acc[i][j] = (floatx4){0.f, 0.f, 0.f, 0.f};

    for (int kk = 0; kk < Dc; kk += BK) {
        __syncthreads();
        stage_ab(Ag, Dc, Bg, Dc, kk, As, Bs, w, lane);
        __syncthreads();
        bf16x8 af[4], bfr[2];
#pragma unroll
        for (int mi = 0; mi < 4; mi++)
            af[mi] = *(const bf16x8*)(As + (Mq + mi * 16 + l15) * BK + l4 * 8);
#pragma unroll
        for (int ni = 0; ni < 2; ni++)
            bfr[ni] = *(const bf16x8*)(Bs + (Nq + ni * 16 + l15) * BK + l4 * 8);
#pragma unroll
        for (int mi = 0; mi < 4; mi++)
#pragma unroll
            for (int ni = 0; ni < 2; ni++)
                acc[mi][ni] = __builtin_amdgcn_mfma_f32_16x16x32_bf16(af[mi], bfr[ni], acc[mi][ni], 0, 0, 0);
    }

#pragma unroll
    for (int mi = 0; mi < 4; mi++) {
#pragma unroll
        for (int r = 0; r < 4; r++) {
            int mloc = Mq + mi * 16 + l4 * 4 + r;
            int gm = m0 + mloc;
            if (gm < cnt) {
                size_t rowbase = (size_t)(moff + gm) * Hc + n0;
#pragma unroll
                for (int ni = 0; ni < 2; ni++) {
                    float g = gelu_tanh(acc[mi][ni][r]);
                    hidden[rowbase + Nq + ni * 16 + l15] = f2bf(g);
                }
            }
        }
    }
}

// GEMM2: out[token, n] += w * sum_h hidden[m,h] * values[e][n,h]
// split-K: blockIdx.z selects K-half (2 x 1024)
__global__ __launch_bounds__(256, 4) void gemm2_kernel(
    const unsigned short* __restrict__ hidden,  // [Pc+PADROWS, 2048] bf16
    const unsigned short* __restrict__ valsb,   // [E, 1024, 2048] bf16
    const int* __restrict__ counts, const int* __restrict__ offs,
    const int* __restrict__ tile_e, const int* __restrict__ tile_m0,
    const int* __restrict__ n_tiles,
    const int* __restrict__ job_token, const float* __restrict__ job_w,
    float* __restrict__ out)
{
    int ty = blockIdx.y;
    if (ty >= *n_tiles) return;
    int e = tile_e[ty], m0 = tile_m0[ty];
    int cnt = counts[e], moff = offs[e];
    int n0 = blockIdx.x * BN;
    int k_begin = blockIdx.z * (Hc / 2);
    int k_end = k_begin + (Hc / 2);
    const unsigned short* Ag = hidden + (size_t)(moff + m0) * Hc;
    const unsigned short* Bg = valsb + (size_t)e * Dc * Hc + (size_t)n0 * Hc;

    __shared__ unsigned short As[BM * BK];
    __shared__ unsigned short Bs[BN * BK];

    int t = threadIdx.x;
    int lane = t & 63, w = t >> 6;
    int Mq = (w & 1) * 64, Nq = (w >> 1) * 32;
    int l15 = lane & 15, l4 = lane >> 4;

    floatx4 acc[4][2];
#pragma unroll
    for (int i = 0; i < 4; i++)
#pragma unroll
        for (int j = 0; j < 2; j++) acc[i][j] = (floatx4){0.f, 0.f, 0.f, 0.f};

    for (int kk = k_begin; kk < k_end; kk += BK) {
        __syncthreads();
        stage_ab(Ag, Hc, Bg, Hc, kk, As, Bs, w, lane);
        __syncthreads();
        bf16x8 af[4], bfr[2];
#pragma unroll
        for (int mi = 0; mi < 4; mi++)
            af[mi] = *(const bf16x8*)(As + (Mq + mi * 16 + l15) * BK + l4 * 8);
#pragma unroll
        for (int ni = 0; ni < 2; ni++)
            bfr[ni] = *(const bf16x8*)(Bs + (Nq + ni * 16 + l15) * BK + l4 * 8);
#pragma unroll
        for (int mi = 0; mi < 4; mi++)
#pragma unroll
            for (int ni = 0; ni < 2; ni++)
                acc[mi][ni] = __builtin_amdgcn_mfma_f32_16x16x32_bf16(af[mi], bfr[ni], acc[mi][ni], 0, 0, 0);
    }

#pragma unroll
    for (int mi = 0; mi < 4; mi++) {
#pragma unroll
        for (int r = 0; r < 4; r++) {
            int mloc = Mq + mi * 16 + l4 * 4 + r;
            int gm = m0 + mloc;
            if (gm < cnt) {
                int tok = job_token[moff + gm];
                float wgt = job_w[moff + gm];
                float* orow = out + (size_t)tok * Dc + n0;
#pragma unroll
                for (int ni = 0; ni < 2; ni++) {
                    atomicAdd(orow + Nq + ni * 16 + l15, wgt * acc[mi][ni][r]);
                }
            }
        }
    }
}

// ---------- workspace layout (bytes) ----------
// counts     @ 0        (32)
// offs       @ 64       (36 -> pad to 128)
// tile_e     @ 128      (160 -> pad 192)
// tile_m0    @ 320      (160 -> pad 192)
// n_tiles    @ 512      (4 -> pad 128)
// job_token  @ 640      (16384)
// job_w      @ 17024    (16384)
// Xg         @ 33408    ((4096+128)*1024*2 = 8650752)
// keysb      @ 8684160  (33554432)
// valsb      @ 42238592 (33554432)
// hidden     @ 75793024 ((4096+128)*2048*2 = 17301504) -> total 93094528 B

extern "C" void kernel_launch(void* const* d_in, const int* in_sizes, int n_in,
                              void* d_out, int out_size, void* d_ws, size_t ws_size,
                              hipStream_t stream) {
    const float* x      = (const float*)d_in[0];
    const float* keys   = (const float*)d_in[1];
    const float* values = (const float*)d_in[2];
    const int*   eidx   = (const int*)d_in[3];
    const float* ew     = (const float*)d_in[4];
    float* out = (float*)d_out;
    char* ws = (char*)d_ws;

    int*   counts    = (int*)(ws + 0);
    int*   offs      = (int*)(ws + 64);
    int*   tile_e    = (int*)(ws + 128);
    int*   tile_m0   = (int*)(ws + 320);
    int*   n_tiles   = (int*)(ws + 512);
    int*   job_token = (int*)(ws + 640);
    float* job_w     = (float*)(ws + 17024);
    unsigned short* Xg     = (unsigned short*)(ws + 33408);
    unsigned short* keysb  = (unsigned short*)(ws + 8684160);
    unsigned short* valsb  = (unsigned short*)(ws + 42238592);
    unsigned short* hidden = (unsigned short*)(ws + 75793024);

    hipMemsetAsync(d_out, 0, (size_t)out_size * 4, stream);   // fp32 accum target

    bucket_kernel<<<1, 256, 0, stream>>>(eidx, ew, counts, offs, tile_e, tile_m0,
                                         n_tiles, job_token, job_w);

    const int n8each = (Ec * Hc * Dc) / 8;   // 2,097,152
    convert2_kernel<<<(2 * n8each) / 256, 256, 0, stream>>>(keys, keysb, values, valsb, n8each);
    gather_kernel<<<Pc, 256, 0, stream>>>(x, job_token, Xg);

    gemm1_kernel<<<dim3(Hc / BN, MAXTILES, 1), 256, 0, stream>>>(
        Xg, keysb, counts, offs, tile_e, tile_m0, n_tiles, hidden);
    gemm2_kernel<<<dim3(Dc / BN, MAXTILES, 2), 256, 0, stream>>>(
        hidden, valsb, counts, offs, tile_e, tile_m0, n_tiles, job_token, job_w, out);
}

// Round 4
// 265.726 us; speedup vs baseline: 1.3161x; 1.0675x over previous
//
#include <hip/hip_runtime.h>

// Problem constants
#define Bc 2
#define Sc 1024
#define Dc 1024
#define Hc 2048
#define Ec 8
#define Kc 2
#define Tc (Bc*Sc)      // 2048 tokens
#define Pc (Tc*Kc)      // 4096 jobs
#define PADROWS 128     // tile-overrun padding for Xg / hidden
#define MAXTILES 40     // sum_e ceil(cnt_e/128) <= 4096/128 + 8 = 40

typedef __bf16 bf16x8 __attribute__((ext_vector_type(8)));
typedef float floatx4 __attribute__((ext_vector_type(4)));
typedef unsigned short ushort4_t __attribute__((ext_vector_type(4)));
typedef unsigned short ushort8_t __attribute__((ext_vector_type(8)));

__device__ inline unsigned short f2bf(float f) {
    unsigned u = __builtin_bit_cast(unsigned, f);
    unsigned r = u + 0x7fffu + ((u >> 16) & 1u);   // RNE
    return (unsigned short)(r >> 16);
}

// flax nn.gelu approximate=True: 0.5v(1+tanh(y)) == v * sigmoid(2y)
__device__ inline float gelu_fast(float v) {
    float z = 1.5957691216057308f * (v + 0.044715f * v * v * v);  // 2y
    return v / (1.0f + __expf(-z));
}

// async global->LDS, 16B per lane; LDS dest = wave-uniform base + lane*16
__device__ inline void gload_lds16(const void* g, void* l) {
    __builtin_amdgcn_global_load_lds((const __attribute__((address_space(1))) unsigned int*)g,
                                     (__attribute__((address_space(3))) unsigned int*)l,
                                     16, 0, 0);
}

// ---------- single-block bucketing: counts + prefix + tile list + job fill ----------
__global__ void bucket_kernel(const int* __restrict__ idx, const float* __restrict__ wts,
                              int* __restrict__ counts, int* __restrict__ offs,
                              int* __restrict__ tile_e, int* __restrict__ tile_m0,
                              int* __restrict__ n_tiles,
                              int* __restrict__ job_token, float* __restrict__ job_w) {
    __shared__ int lc[Ec], lf[Ec], lo[Ec];
    int t = threadIdx.x;
    if (t < Ec) { lc[t] = 0; lf[t] = 0; }
    __syncthreads();
    int myid[Pc / 256];
#pragma unroll
    for (int j = 0; j < Pc / 256; j++) {
        int i = t + j * 256;
        myid[j] = idx[i];
        atomicAdd(&lc[myid[j]], 1);
    }
    __syncthreads();
    if (t == 0) {
        int s = 0, tt = 0;
        for (int e = 0; e < Ec; e++) {
            lo[e] = s; offs[e] = s; counts[e] = lc[e];
            for (int m0 = 0; m0 < lc[e]; m0 += 128) { tile_e[tt] = e; tile_m0[tt] = m0; tt++; }
            s += lc[e];
        }
        offs[Ec] = s;
        *n_tiles = tt;
    }
    __syncthreads();
#pragma unroll
    for (int j = 0; j < Pc / 256; j++) {
        int i = t + j * 256;
        int e = myid[j];
        int pos = lo[e] + atomicAdd(&lf[e], 1);
        job_token[pos] = i >> 1;          // i = token*K + k
        job_w[pos] = wts[i];
    }
}

// ---------- fp32 -> bf16 conversion of BOTH weight tensors in one launch ----------
__global__ void convert2_kernel(const float* __restrict__ a, unsigned short* __restrict__ da,
                                const float* __restrict__ b, unsigned short* __restrict__ db,
                                int n8each) {
    int i = blockIdx.x * 256 + threadIdx.x;
    const float* s; unsigned short* d; int j;
    if (i < n8each) { s = a; d = da; j = i; }
    else            { s = b; d = db; j = i - n8each; if (j >= n8each) return; }
    float4 v0 = ((const float4*)s)[2 * j];
    float4 v1 = ((const float4*)s)[2 * j + 1];
    ushort8_t o = { f2bf(v0.x), f2bf(v0.y), f2bf(v0.z), f2bf(v0.w),
                    f2bf(v1.x), f2bf(v1.y), f2bf(v1.z), f2bf(v1.w) };
    ((ushort8_t*)d)[j] = o;
}

// ---------- gather selected x rows into compact bf16 matrix ----------
__global__ void gather_kernel(const float* __restrict__ x, const int* __restrict__ job_token,
                              unsigned short* __restrict__ Xg) {
    int row = blockIdx.x;                  // 0..Pc-1
    int tok = job_token[row];
    int j = threadIdx.x;                   // 256 threads x 4 elems = 1024
    float4 v = ((const float4*)(x + (size_t)tok * Dc))[j];
    ushort4_t o = { f2bf(v.x), f2bf(v.y), f2bf(v.z), f2bf(v.w) };
    *(ushort4_t*)(Xg + (size_t)row * Dc + j * 4) = o;
}

// ---------- GEMM tile config ----------
#define BM 128
#define BN 128
#define BK 64
// LDS tile: 128 rows x 64 bf16 (128B = 8 chunks of 16B per row).
// Physical chunk position = logical_chunk ^ (row & 7)  (bank-conflict swizzle).
// global_load_lds: lane -> row = base+(lane>>3), phys chunk = lane&7, so lane
// fetches global logical chunk (lane&7)^(row&7). 8x128B segments per inst.

__device__ inline void stage_tile64(const unsigned short* __restrict__ g0, size_t ld, int kk,
                                    unsigned short* lds, int w, int lane) {
    int rr = lane >> 3;            // 0..7 row within 8-row group
    int cp = lane & 7;             // physical chunk
#pragma unroll
    for (int j = 0; j < 4; j++) {
        int row = w * 32 + j * 8 + rr;
        int cl = cp ^ (row & 7);   // logical chunk to fetch
        const char* g = (const char*)(g0 + (size_t)row * ld + kk + cl * 8);
        char* l = (char*)lds + (size_t)(w * 32 + j * 8) * 128;
        gload_lds16(g, l);
    }
}

// GEMM1: hidden[m, n] = gelu( sum_d Xg[m,d] * keys[e][n,d] ),  K=1024, N=2048
__global__ __launch_bounds__(256, 2) void gemm1_kernel(
    const unsigned short* __restrict__ Xg,      // [Pc+PADROWS, 1024] bf16
    const unsigned short* __restrict__ keysb,   // [E, 2048, 1024] bf16
    const int* __restrict__ counts, const int* __restrict__ offs,
    const int* __restrict__ tile_e, const int* __restrict__ tile_m0,
    const int* __restrict__ n_tiles,
    unsigned short* __restrict__ hidden)        // [Pc+PADROWS, 2048] bf16
{
    int ty = blockIdx.y;
    if (ty >= *n_tiles) return;
    int e = tile_e[ty], m0 = tile_m0[ty];
    int cnt = counts[e], moff = offs[e];
    int n0 = blockIdx.x * BN;
    const unsigned short* Ag = Xg + (size_t)(moff + m0) * Dc;
    const unsigned short* Bg = keysb + (size_t)e * Hc * Dc + (size_t)n0 * Dc;

    __shared__ unsigned short As[BM * BK];
    __shared__ unsigned short Bs[BN * BK];

    int t = threadIdx.x;
    int lane = t & 63, w = t >> 6;
    int Mq = (w & 1) * 64, Nq = (w >> 1) * 64;
    int l15 = lane & 15, l4 = lane >> 4;
    int rx = l15 & 7;   // row-dependent swizzle factor for fragment reads

    floatx4 acc[4][4];
#pragma unroll
    for (int i = 0; i < 4; i++)
#pragma unroll
        for (int j = 0; j < 4; j++) acc[i][j] = (floatx4){0.f, 0.f, 0.f, 0.f};

    for (int kk = 0; kk < Dc; kk += BK) {
        __syncthreads();
        stage_tile64(Ag, Dc, kk, As, w, lane);
        stage_tile64(Bg, Dc, kk, Bs, w, lane);
        __syncthreads();
#pragma unroll
        for (int s = 0; s < 2; s++) {
            bf16x8 af[4], bfr[4];
#pragma unroll
            for (int mi = 0; mi < 4; mi++)
                af[mi] = *(const bf16x8*)(As + (Mq + mi * 16 + l15) * BK + (((s * 4 + l4) ^ rx) * 8));
#pragma unroll
            for (int ni = 0; ni < 4; ni++)
                bfr[ni] = *(const bf16x8*)(Bs + (Nq + ni * 16 + l15) * BK + (((s * 4 + l4) ^ rx) * 8));
#pragma unroll
            for (int mi = 0; mi < 4; mi++)
#pragma unroll
                for (int ni = 0; ni < 4; ni++)
                    acc[mi][ni] = __builtin_amdgcn_mfma_f32_16x16x32_bf16(af[mi], bfr[ni], acc[mi][ni], 0, 0, 0);
        }
    }

#pragma unroll
    for (int mi = 0; mi < 4; mi++) {
#pragma unroll
        for (int r = 0; r < 4; r++) {
            int mloc = Mq + mi * 16 + l4 * 4 + r;
            int gm = m0 + mloc;
            if (gm < cnt) {
                size_t rowbase = (size_t)(moff + gm) * Hc + n0;
#pragma unroll
                for (int ni = 0; ni < 4; ni++) {
                    float g = gelu_fast(acc[mi][ni][r]);
                    hidden[rowbase + Nq + ni * 16 + l15] = f2bf(g);
                }
            }
        }
    }
}

// GEMM2: out[token, n] += w * sum_h hidden[m,h] * values[e][n,h]
// split-K: blockIdx.z selects K-half (2 x 1024)
__global__ __launch_bounds__(256, 2) void gemm2_kernel(
    const unsigned short* __restrict__ hidden,  // [Pc+PADROWS, 2048] bf16
    const unsigned short* __restrict__ valsb,   // [E, 1024, 2048] bf16
    const int* __restrict__ counts, const int* __restrict__ offs,
    const int* __restrict__ tile_e, const int* __restrict__ tile_m0,
    const int* __restrict__ n_tiles,
    const int* __restrict__ job_token, const float* __restrict__ job_w,
    float* __restrict__ out)
{
    int ty = blockIdx.y;
    if (ty >= *n_tiles) return;
    int e = tile_e[ty], m0 = tile_m0[ty];
    int cnt = counts[e], moff = offs[e];
    int n0 = blockIdx.x * BN;
    int k_begin = blockIdx.z * (Hc / 2);
    int k_end = k_begin + (Hc / 2);
    const unsigned short* Ag = hidden + (size_t)(moff + m0) * Hc;
    const unsigned short* Bg = valsb + (size_t)e * Dc * Hc + (size_t)n0 * Hc;

    __shared__ unsigned short As[BM * BK];
    __shared__ unsigned short Bs[BN * BK];

    int t = threadIdx.x;
    int lane = t & 63, w = t >> 6;
    int Mq = (w & 1) * 64, Nq = (w >> 1) * 64;
    int l15 = lane & 15, l4 = lane >> 4;
    int rx = l15 & 7;

    floatx4 acc[4][4];
#pragma unroll
    for (int i = 0; i < 4; i++)
#pragma unroll
        for (int j = 0; j < 4; j++) acc[i][j] = (floatx4){0.f, 0.f, 0.f, 0.f};

    for (int kk = k_begin; kk < k_end; kk += BK) {
        __syncthreads();
        stage_tile64(Ag, Hc, kk, As, w, lane);
        stage_tile64(Bg, Hc, kk, Bs, w, lane);
        __syncthreads();
#pragma unroll
        for (int s = 0; s < 2; s++) {
            bf16x8 af[4], bfr[4];
#pragma unroll
            for (int mi = 0; mi < 4; mi++)
                af[mi] = *(const bf16x8*)(As + (Mq + mi * 16 + l15) * BK + (((s * 4 + l4) ^ rx) * 8));
#pragma unroll
            for (int ni = 0; ni < 4; ni++)
                bfr[ni] = *(const bf16x8*)(Bs + (Nq + ni * 16 + l15) * BK + (((s * 4 + l4) ^ rx) * 8));
#pragma unroll
            for (int mi = 0; mi < 4; mi++)
#pragma unroll
                for (int ni = 0; ni < 4; ni++)
                    acc[mi][ni] = __builtin_amdgcn_mfma_f32_16x16x32_bf16(af[mi], bfr[ni], acc[mi][ni], 0, 0, 0);
        }
    }

#pragma unroll
    for (int mi = 0; mi < 4; mi++) {
#pragma unroll
        for (int r = 0; r < 4; r++) {
            int mloc = Mq + mi * 16 + l4 * 4 + r;
            int gm = m0 + mloc;
            if (gm < cnt) {
                int tok = job_token[moff + gm];
                float wgt = job_w[moff + gm];
                float* orow = out + (size_t)tok * Dc + n0;
#pragma unroll
                for (int ni = 0; ni < 4; ni++) {
                    atomicAdd(orow + Nq + ni * 16 + l15, wgt * acc[mi][ni][r]);
                }
            }
        }
    }
}

// ---------- workspace layout (bytes) ----------
// counts     @ 0        (32)
// offs       @ 64       (36 -> pad to 128)
// tile_e     @ 128      (160 -> pad 192)
// tile_m0    @ 320      (160 -> pad 192)
// n_tiles    @ 512      (4 -> pad 128)
// job_token  @ 640      (16384)
// job_w      @ 17024    (16384)
// Xg         @ 33408    ((4096+128)*1024*2 = 8650752)
// keysb      @ 8684160  (33554432)
// valsb      @ 42238592 (33554432)
// hidden     @ 75793024 ((4096+128)*2048*2 = 17301504) -> total 93094528 B

extern "C" void kernel_launch(void* const* d_in, const int* in_sizes, int n_in,
                              void* d_out, int out_size, void* d_ws, size_t ws_size,
                              hipStream_t stream) {
    const float* x      = (const float*)d_in[0];
    const float* keys   = (const float*)d_in[1];
    const float* values = (const float*)d_in[2];
    const int*   eidx   = (const int*)d_in[3];
    const float* ew     = (const float*)d_in[4];
    float* out = (float*)d_out;
    char* ws = (char*)d_ws;

    int*   counts    = (int*)(ws + 0);
    int*   offs      = (int*)(ws + 64);
    int*   tile_e    = (int*)(ws + 128);
    int*   tile_m0   = (int*)(ws + 320);
    int*   n_tiles   = (int*)(ws + 512);
    int*   job_token = (int*)(ws + 640);
    float* job_w     = (float*)(ws + 17024);
    unsigned short* Xg     = (unsigned short*)(ws + 33408);
    unsigned short* keysb  = (unsigned short*)(ws + 8684160);
    unsigned short* valsb  = (unsigned short*)(ws + 42238592);
    unsigned short* hidden = (unsigned short*)(ws + 75793024);

    hipMemsetAsync(d_out, 0, (size_t)out_size * 4, stream);   // fp32 accum target

    bucket_kernel<<<1, 256, 0, stream>>>(eidx, ew, counts, offs, tile_e, tile_m0,
                                         n_tiles, job_token, job_w);

    const int n8each = (Ec * Hc * Dc) / 8;   // 2,097,152
    convert2_kernel<<<(2 * n8each) / 256, 256, 0, stream>>>(keys, keysb, values, valsb, n8each);
    gather_kernel<<<Pc, 256, 0, stream>>>(x, job_token, Xg);

    gemm1_kernel<<<dim3(Hc / BN, MAXTILES, 1), 256, 0, stream>>>(
        Xg, keysb, counts, offs, tile_e, tile_m0, n_tiles, hidden);
    gemm2_kernel<<<dim3(Dc / BN, MAXTILES, 2), 256, 0, stream>>>(
        hidden, valsb, counts, offs, tile_e, tile_m0, n_tiles, job_token, job_w, out);
}